// Round 1
// baseline (599.138 us; speedup 1.0000x reference)
//
#include <hip/hip_runtime.h>
#include <math.h>

#define B_ 16
#define L_ 128
#define D_ 768
#define H1_ 770
#define OUT_ 40
#define NPAIRS 3405     // sum over i of min(30, 128-i)
#define NCOLS 1540      // U (770) || V (770)
#define P_ 16           // pairs per block in pair kernel

// ---------------------------------------------------------------------------
// Kernel 1: Y[2048][1540] = X[2048][768] @ W1'[768][1540]
//   X row m = b*128+l  ->  hidden[(b*129 + 1 + l)*768]   (skips the CLS slot)
//   W1' col n < 770  -> W1[k][n]        (W1i)
//   W1' col n >= 770 -> W1[768+k][n-770] (W1j)
// 64x64 tile, BK=16, 256 threads, 4x4 microtile per thread. fp32 vector ALU.
// ---------------------------------------------------------------------------
#define BM 64
#define BN 64
#define BK 16

__global__ __launch_bounds__(256) void gemm_kernel(
    const float* __restrict__ hidden, const float* __restrict__ W1,
    float* __restrict__ Y)
{
  __shared__ float As[BK][BM + 4];
  __shared__ float Bs[BK][BN + 4];
  const int tid = threadIdx.x;
  const int tx = tid & 15, ty = tid >> 4;
  const int row0 = blockIdx.y * BM;
  const int col0 = blockIdx.x * BN;

  float acc[4][4] = {};

  for (int kt = 0; kt < D_; kt += BK) {
    // A tile: 64 rows x 16 k. consecutive tid -> consecutive k (coalesced runs)
    #pragma unroll
    for (int it = 0; it < (BM * BK) / 256; ++it) {
      int idx = tid + it * 256;
      int m = idx >> 4, k = idx & 15;
      int row = row0 + m;
      int b = row >> 7;                       // row / 128
      As[k][m] = hidden[(row + b + 1) * D_ + kt + k];
    }
    // B tile: 16 k x 64 cols. consecutive tid -> consecutive col (coalesced)
    #pragma unroll
    for (int it = 0; it < (BK * BN) / 256; ++it) {
      int idx = tid + it * 256;
      int k = idx >> 6, n = idx & 63;
      int col = col0 + n;
      float v = 0.f;
      if (col < NCOLS) {
        int kg = kt + k;
        int r = (col < H1_) ? kg : (D_ + kg);
        int c = (col < H1_) ? col : (col - H1_);
        v = W1[r * H1_ + c];
      }
      Bs[k][n] = v;
    }
    __syncthreads();

    #pragma unroll
    for (int kk = 0; kk < BK; ++kk) {
      float a[4], b[4];
      #pragma unroll
      for (int i = 0; i < 4; ++i) a[i] = As[kk][ty * 4 + i];
      #pragma unroll
      for (int i = 0; i < 4; ++i) b[i] = Bs[kk][tx * 4 + i];
      #pragma unroll
      for (int i = 0; i < 4; ++i)
        #pragma unroll
        for (int j = 0; j < 4; ++j)
          acc[i][j] += a[i] * b[j];
    }
    __syncthreads();
  }

  #pragma unroll
  for (int i = 0; i < 4; ++i) {
    int row = row0 + ty * 4 + i;
    #pragma unroll
    for (int j = 0; j < 4; ++j) {
      int col = col0 + tx * 4 + j;
      if (col < NCOLS) Y[row * NCOLS + col] = acc[i][j];
    }
  }
}

// ---------------------------------------------------------------------------
// pair index -> (i, j). Row-major enumeration of the band mask:
// i in [0,98]: 30 entries each (2970 total); i in [99,127]: 29..1 entries.
// ---------------------------------------------------------------------------
__device__ inline void pair_ij(int n, int& i, int& j) {
  if (n < 2970) {
    i = n / 30;
    j = i + (n - i * 30);
  } else {
    int m = n - 2970;
    int r = 0, w = 29;
    while (m >= w) { m -= w; --w; ++r; }
    i = 99 + r;
    j = i + m;
  }
}

// ---------------------------------------------------------------------------
// Kernel 2: per (batch, pair): h = relu(U[b,i] + V[b,j] + ind*w1c + b1)  (770)
//           logits = h @ W2 + b2  (40), out = log_softmax(logits)
// One block handles P_=16 pairs of one batch. h staged in LDS.
// ---------------------------------------------------------------------------
__global__ __launch_bounds__(256) void pair_kernel(
    const float* __restrict__ Y, const int* __restrict__ spans,
    const float* __restrict__ W1, const float* __restrict__ b1,
    const float* __restrict__ W2, const float* __restrict__ b2,
    float* __restrict__ out)
{
  __shared__ float hs[P_][H1_ + 1];
  __shared__ float lg[P_][OUT_];
  __shared__ float red[P_];
  __shared__ int   pi[P_], pj[P_];
  __shared__ float pind[P_];

  const int tid = threadIdx.x;
  const int bb = blockIdx.y;
  const int pair0 = blockIdx.x * P_;

  if (tid < P_) {
    int pair = pair0 + tid;
    int i = 0, j = 0;
    if (pair < NPAIRS) pair_ij(pair, i, j);
    pi[tid] = i; pj[tid] = j;
    int s = spans[2 * bb], e = spans[2 * bb + 1];
    pind[tid] = (i == s && j == e) ? 2.0f
              : ((i >= s && j <= e) ? 1.0f : 0.0f);
  }
  __syncthreads();

  const float* w1c = W1 + 2 * D_ * H1_;   // row 1536 of W1

  // phase 1: build relu(h) for 16 pairs into LDS
  for (int v = tid; v < P_ * H1_; v += 256) {
    int p = v / H1_;
    int k = v - p * H1_;
    const float* u  = Y + (bb * L_ + pi[p]) * NCOLS;         // U part
    const float* vv = Y + (bb * L_ + pj[p]) * NCOLS + H1_;   // V part
    float h = u[k] + vv[k] + pind[p] * w1c[k] + b1[k];
    hs[p][k] = fmaxf(h, 0.f);
  }
  __syncthreads();

  // phase 2: logits (770 -> 40 GEMV per pair)
  for (int item = tid; item < P_ * OUT_; item += 256) {
    int p = item / OUT_;
    int o = item - p * OUT_;
    float acc = b2[o];
    const float* hp = hs[p];
    #pragma unroll 5
    for (int k = 0; k < H1_; ++k)
      acc += hp[k] * W2[k * OUT_ + o];
    lg[p][o] = acc;
  }
  __syncthreads();

  // log-softmax reduction per pair (tiny: 16 threads x 2x40 loop)
  if (tid < P_) {
    float mx = -1e30f;
    #pragma unroll
    for (int o = 0; o < OUT_; ++o) mx = fmaxf(mx, lg[tid][o]);
    float s = 0.f;
    #pragma unroll
    for (int o = 0; o < OUT_; ++o) s += expf(lg[tid][o] - mx);
    red[tid] = mx + logf(s);
  }
  __syncthreads();

  for (int item = tid; item < P_ * OUT_; item += 256) {
    int p = item / OUT_;
    int o = item - p * OUT_;
    int pair = pair0 + p;
    if (pair < NPAIRS)
      out[(bb * NPAIRS + pair) * OUT_ + o] = lg[p][o] - red[p];
  }
}

// ---------------------------------------------------------------------------
extern "C" void kernel_launch(void* const* d_in, const int* in_sizes, int n_in,
                              void* d_out, int out_size, void* d_ws, size_t ws_size,
                              hipStream_t stream) {
  const float* hidden = (const float*)d_in[0];   // (16,129,768) f32
  const int*   spans  = (const int*)d_in[1];     // (16,2) i32
  // d_in[2] = token_num (128, constant), d_in[3] = span mask (derived analytically)
  const float* W1 = (const float*)d_in[4];       // (1537,770) f32
  const float* b1 = (const float*)d_in[5];       // (770,)
  const float* W2 = (const float*)d_in[6];       // (770,40)
  const float* b2 = (const float*)d_in[7];       // (40,)
  float* out = (float*)d_out;                    // (16,3405,40) f32
  float* Y = (float*)d_ws;                       // 2048 x 1540 f32 = 12.6 MB

  gemm_kernel<<<dim3((NCOLS + BN - 1) / BN, 2048 / BM), 256, 0, stream>>>(hidden, W1, Y);
  pair_kernel<<<dim3((NPAIRS + P_ - 1) / P_, B_), 256, 0, stream>>>(
      Y, spans, W1, b1, W2, b2, out);
}

// Round 2
// 353.803 us; speedup vs baseline: 1.6934x; 1.6934x over previous
//
#include <hip/hip_runtime.h>
#include <math.h>

#define B_ 16
#define L_ 128
#define D_ 768
#define H1_ 770
#define OUT_ 40
#define NPAIRS 3405     // sum over i of min(30, 128-i)
#define NLOG 1540       // logical cols of Y: U(770) || V(770)
#define YSTRIDE 1544    // padded row: U at [0,770), pad, V at [772,1542)
#define VOFF 772

// ---------------------------------------------------------------------------
// Kernel 1: Y[2048][*] = X[2048][768] @ [W1i | W1j]  (padded layout)
// 128x128 tile, BK=16, 256 threads, 8x8 microtile (split 4+4 at +64 offset).
// ---------------------------------------------------------------------------
#define BM 128
#define BN 128
#define BK 16

__global__ __launch_bounds__(256) void gemm_kernel(
    const float* __restrict__ hidden, const float* __restrict__ W1,
    float* __restrict__ Y)
{
  __shared__ float As[BK][BM + 4];
  __shared__ float Bs[BK][BN + 4];
  const int tid = threadIdx.x;
  const int tx = tid & 15;     // col group 0..15
  const int ty = tid >> 4;     // row group 0..15
  const int row0 = blockIdx.y * BM;
  const int col0 = blockIdx.x * BN;

  float acc[8][8] = {};

  for (int kt = 0; kt < D_; kt += BK) {
    #pragma unroll
    for (int it = 0; it < (BM * BK) / 256; ++it) {      // A: 128 rows x 16 k
      int idx = tid + it * 256;
      int m = idx >> 4, k = idx & 15;
      int row = row0 + m;
      int b = row >> 7;
      As[k][m] = hidden[(row + b + 1) * D_ + kt + k];
    }
    #pragma unroll
    for (int it = 0; it < (BK * BN) / 256; ++it) {      // B: 16 k x 128 n
      int idx = tid + it * 256;
      int k = idx >> 7, n = idx & 127;
      int col = col0 + n;
      float v = 0.f;
      if (col < NLOG) {
        int kg = kt + k;
        v = (col < H1_) ? W1[kg * H1_ + col] : W1[(D_ + kg) * H1_ + (col - H1_)];
      }
      Bs[k][n] = v;
    }
    __syncthreads();

    #pragma unroll
    for (int kk = 0; kk < BK; ++kk) {
      float4 a0 = *(const float4*)&As[kk][ty * 4];
      float4 a1 = *(const float4*)&As[kk][64 + ty * 4];
      float4 b0 = *(const float4*)&Bs[kk][tx * 4];
      float4 b1v = *(const float4*)&Bs[kk][64 + tx * 4];
      float a[8] = {a0.x, a0.y, a0.z, a0.w, a1.x, a1.y, a1.z, a1.w};
      float b[8] = {b0.x, b0.y, b0.z, b0.w, b1v.x, b1v.y, b1v.z, b1v.w};
      #pragma unroll
      for (int i = 0; i < 8; ++i)
        #pragma unroll
        for (int j = 0; j < 8; ++j)
          acc[i][j] += a[i] * b[j];
    }
    __syncthreads();
  }

  #pragma unroll
  for (int i = 0; i < 8; ++i) {
    int row = row0 + ((i < 4) ? ty * 4 + i : 64 + ty * 4 + (i - 4));
    #pragma unroll
    for (int j = 0; j < 8; ++j) {
      int col = col0 + ((j < 4) ? tx * 4 + j : 64 + tx * 4 + (j - 4));
      if (col < NLOG) {
        int pc = (col < H1_) ? col : col + 2;   // padded layout
        Y[row * YSTRIDE + pc] = acc[i][j];
      }
    }
  }
}

// ---------------------------------------------------------------------------
// pair index -> (i, j). Row-major over band mask (i<=98: 30 each; then 29..1)
// ---------------------------------------------------------------------------
__device__ inline void pair_ij(int n, int& i, int& j) {
  if (n < 2970) {
    i = n / 30;
    j = i + (n - i * 30);
  } else {
    int m = n - 2970;
    int r = 0, w = 29;
    while (m >= w) { m -= w; --w; ++r; }
    i = 99 + r;
    j = i + m;
  }
}

// ---------------------------------------------------------------------------
// Kernel 2: tall-skinny GEMM  C[pairs x 40] = relu(H)[pairs x 770] @ W2
// 128 pairs/block, K chunks of 64, 4 pairs x 5 outs per thread (float4 over k)
// ---------------------------------------------------------------------------
#define PPB 128
#define CK 64
#define HS_S 68      // hs row stride (16B aligned, read-conflict-free)

__global__ __launch_bounds__(256) void pair_kernel(
    const float* __restrict__ Y, const int* __restrict__ spans,
    const float* __restrict__ W1, const float* __restrict__ b1,
    const float* __restrict__ W2, const float* __restrict__ b2,
    float* __restrict__ out)
{
  __shared__ float hs[PPB][HS_S];     // 34.8 KB
  __shared__ float w2t[OUT_][HS_S];   // 10.9 KB (transposed W2 chunk)
  __shared__ int   pi[PPB], pj[PPB];
  __shared__ float pind[PPB];

  const int tid = threadIdx.x;
  const int bb = blockIdx.y;
  const int pair0 = blockIdx.x * PPB;
  const int tr = tid >> 3;            // 0..31 : pair group (4 pairs)
  const int tc = tid & 7;             // 0..7  : out group (5 outs)
  const int p0 = tr * 4;

  const float* w1c = W1 + 1536 * H1_;

  if (tid < PPB) {
    int pair = pair0 + tid;
    int i = 0, j = 0;
    if (pair < NPAIRS) pair_ij(pair, i, j);
    pi[tid] = i; pj[tid] = j;
    int s = spans[2 * bb], e = spans[2 * bb + 1];
    pind[tid] = (i == s && j == e) ? 2.0f : ((i >= s && j <= e) ? 1.0f : 0.0f);
  }
  __syncthreads();

  // assembly role: 2 threads per pair, 32 k-elements each
  const int myp = tid >> 1;
  const int half = tid & 1;
  const float ind_my = pind[myp];
  const float* urow = Y + (bb * L_ + pi[myp]) * YSTRIDE;
  const float* vrow = Y + (bb * L_ + pj[myp]) * YSTRIDE + VOFF;

  float acc[4][5] = {};

  for (int k0 = 0; k0 < 768; k0 += CK) {
    __syncthreads();   // previous FMA phase done with hs/w2t

    // stage w2t transposed: global read perfectly coalesced
    #pragma unroll
    for (int it = 0; it < (CK * OUT_) / 256; ++it) {   // 10
      int idx = tid + it * 256;
      int kk = idx / OUT_;
      int o  = idx - kk * OUT_;
      w2t[o][kk] = W2[k0 * OUT_ + idx];
    }
    // stage relu(h): float4 U,V,b1,w1c loads
    {
      const float4* u4 = (const float4*)(urow + k0);
      const float4* v4 = (const float4*)(vrow + k0);
      const float4* b4 = (const float4*)(b1 + k0);
      const float4* c4 = (const float4*)(w1c + k0);
      #pragma unroll
      for (int m = 0; m < 8; ++m) {
        int q = half * 8 + m;
        float4 u = u4[q], v = v4[q], bv = b4[q], cv = c4[q];
        float4 r;
        r.x = fmaxf(u.x + v.x + ind_my * cv.x + bv.x, 0.f);
        r.y = fmaxf(u.y + v.y + ind_my * cv.y + bv.y, 0.f);
        r.z = fmaxf(u.z + v.z + ind_my * cv.z + bv.z, 0.f);
        r.w = fmaxf(u.w + v.w + ind_my * cv.w + bv.w, 0.f);
        *(float4*)&hs[myp][q * 4] = r;
      }
    }
    __syncthreads();

    // FMA phase: 16 x (9 ds_read_b128 -> 80 FMA)
    #pragma unroll 4
    for (int kk = 0; kk < CK; kk += 4) {
      float4 h[4], w[5];
      #pragma unroll
      for (int i = 0; i < 4; ++i) h[i] = *(const float4*)&hs[p0 + i][kk];
      #pragma unroll
      for (int j = 0; j < 5; ++j) w[j] = *(const float4*)&w2t[tc * 5 + j][kk];
      #pragma unroll
      for (int i = 0; i < 4; ++i)
        #pragma unroll
        for (int j = 0; j < 5; ++j) {
          acc[i][j] += h[i].x * w[j].x;
          acc[i][j] += h[i].y * w[j].y;
          acc[i][j] += h[i].z * w[j].z;
          acc[i][j] += h[i].w * w[j].w;
        }
    }
  }

  // K tail: k = 768, 769 straight from global (L1/L2-hot)
  {
    float wc8 = w1c[768], wc9 = w1c[769];
    float bb8 = b1[768],  bb9 = b1[769];
    float w8[5], w9[5];
    #pragma unroll
    for (int j = 0; j < 5; ++j) {
      w8[j] = W2[768 * OUT_ + tc * 5 + j];
      w9[j] = W2[769 * OUT_ + tc * 5 + j];
    }
    #pragma unroll
    for (int i = 0; i < 4; ++i) {
      int p = p0 + i;
      const float* ur = Y + (bb * L_ + pi[p]) * YSTRIDE;
      const float* vr = Y + (bb * L_ + pj[p]) * YSTRIDE + VOFF;
      float ind = pind[p];
      float h8 = fmaxf(ur[768] + vr[768] + ind * wc8 + bb8, 0.f);
      float h9 = fmaxf(ur[769] + vr[769] + ind * wc9 + bb9, 0.f);
      #pragma unroll
      for (int j = 0; j < 5; ++j)
        acc[i][j] += h8 * w8[j] + h9 * w9[j];
    }
  }

  // epilogue: +b2, log-softmax across the 8 lanes (tc) holding this pair
  float b2v[5];
  #pragma unroll
  for (int j = 0; j < 5; ++j) b2v[j] = b2[tc * 5 + j];

  #pragma unroll
  for (int i = 0; i < 4; ++i) {
    float l[5];
    #pragma unroll
    for (int j = 0; j < 5; ++j) l[j] = acc[i][j] + b2v[j];
    float mx = l[0];
    #pragma unroll
    for (int j = 1; j < 5; ++j) mx = fmaxf(mx, l[j]);
    mx = fmaxf(mx, __shfl_xor(mx, 1, 64));
    mx = fmaxf(mx, __shfl_xor(mx, 2, 64));
    mx = fmaxf(mx, __shfl_xor(mx, 4, 64));
    float s = 0.f;
    #pragma unroll
    for (int j = 0; j < 5; ++j) s += expf(l[j] - mx);
    s += __shfl_xor(s, 1, 64);
    s += __shfl_xor(s, 2, 64);
    s += __shfl_xor(s, 4, 64);
    float lsd = mx + logf(s);

    int pair = pair0 + p0 + i;
    if (pair < NPAIRS) {
      float* op = out + ((size_t)(bb * NPAIRS + pair)) * OUT_ + tc * 5;
      #pragma unroll
      for (int j = 0; j < 5; ++j) op[j] = l[j] - lsd;
    }
  }
}

// ---------------------------------------------------------------------------
extern "C" void kernel_launch(void* const* d_in, const int* in_sizes, int n_in,
                              void* d_out, int out_size, void* d_ws, size_t ws_size,
                              hipStream_t stream) {
  const float* hidden = (const float*)d_in[0];   // (16,129,768) f32
  const int*   spans  = (const int*)d_in[1];     // (16,2) i32
  const float* W1 = (const float*)d_in[4];       // (1537,770) f32
  const float* b1 = (const float*)d_in[5];       // (770,)
  const float* W2 = (const float*)d_in[6];       // (770,40)
  const float* b2 = (const float*)d_in[7];       // (40,)
  float* out = (float*)d_out;                    // (16,3405,40) f32
  float* Y = (float*)d_ws;                       // 2048 x 1544 f32 = 12.65 MB

  gemm_kernel<<<dim3((NLOG + BN - 1) / BN, 2048 / BM), 256, 0, stream>>>(hidden, W1, Y);
  pair_kernel<<<dim3((NPAIRS + PPB - 1) / PPB, B_), 256, 0, stream>>>(
      Y, spans, W1, b1, W2, b2, out);
}

// Round 3
// 210.802 us; speedup vs baseline: 2.8422x; 1.6784x over previous
//
#include <hip/hip_runtime.h>
#include <math.h>

#define B_ 16
#define L_ 128
#define D_ 768
#define H1_ 770
#define OUT_ 40
#define NPAIRS 3405     // sum over i of min(30, 128-i)
#define NLOG 1540       // logical cols of Y: U(770) || V(770)
#define YSTRIDE 1544    // padded row: U at [0,770), pad, V at [772,1542)
#define VOFF 772

typedef __attribute__((ext_vector_type(8))) short bf16x8;
typedef __attribute__((ext_vector_type(8))) unsigned short u16x8;
typedef __attribute__((ext_vector_type(4))) float f32x4;

__device__ inline unsigned short f2bf(float f) {
  unsigned int u = __builtin_bit_cast(unsigned int, f);
  u += 0x7fffu + ((u >> 16) & 1u);          // round-to-nearest-even
  return (unsigned short)(u >> 16);
}

// ---------------------------------------------------------------------------
// Kernel 0: W1T[n][k] = bf16( W1'[k][n] )   n<770 -> W1[k][n], else W1[768+k][n-770]
// 32x32 LDS transpose tiles.
// ---------------------------------------------------------------------------
__global__ __launch_bounds__(256) void w1t_kernel(
    const float* __restrict__ W1, unsigned short* __restrict__ W1T)
{
  __shared__ float t[32][33];
  const int tx = threadIdx.x & 31, ty = threadIdx.x >> 5;   // ty 0..7
  const int n0 = blockIdx.x * 32, k0 = blockIdx.y * 32;
  #pragma unroll
  for (int r = 0; r < 4; ++r) {
    int k = k0 + ty + r * 8, n = n0 + tx;
    float v = 0.f;
    if (n < H1_)       v = W1[k * H1_ + n];
    else if (n < NLOG) v = W1[(D_ + k) * H1_ + (n - H1_)];
    t[ty + r * 8][tx] = v;
  }
  __syncthreads();
  #pragma unroll
  for (int r = 0; r < 4; ++r) {
    int n = n0 + ty + r * 8, k = k0 + tx;
    if (n < NLOG) W1T[(size_t)n * D_ + k] = f2bf(t[tx][ty + r * 8]);
  }
}

// ---------------------------------------------------------------------------
// Kernel 1 (MFMA): Y[2048][pad] = X[2048][768]_bf16 @ W1T^T
// 64x64 tile, BK=64, 256 thr / 4 waves, each wave 32x32 via 2x2 16x16x32 MFMA.
// LDS row stride 72 bf16 = 144 B = 16*9 -> bank-uniform b128 access.
// ---------------------------------------------------------------------------
#define AS_S 72

__global__ __launch_bounds__(256) void gemm1_mfma(
    const float* __restrict__ hidden, const unsigned short* __restrict__ W1T,
    float* __restrict__ Y)
{
  __shared__ unsigned short As[64][AS_S];   // 9.2 KB
  __shared__ unsigned short Bt[64][AS_S];   // 9.2 KB
  const int tid = threadIdx.x;
  const int row0 = blockIdx.y * 64, col0 = blockIdx.x * 64;
  const int lane = tid & 63, w = tid >> 6;
  const int lm = lane & 15, q = lane >> 4;
  const int m0 = (w >> 1) * 32, n0 = (w & 1) * 32;

  f32x4 acc[2][2] = {};

  // A staging: thread owns (row a_m, 16 k's starting a_kq*16)
  const int a_kq = tid & 3, a_m = tid >> 2;
  const int grow = row0 + a_m;
  const float* arow = hidden + (size_t)(grow + (grow >> 7) + 1) * D_ + a_kq * 16;
  // B staging: thread owns (col b_n(+32), 8 k's starting b_ko*8)
  const int b_ko = tid & 7, b_n = tid >> 3;

  for (int k0 = 0; k0 < D_; k0 += 64) {
    // ---- stage A (fp32 -> bf16) ----
    float4 f0 = *(const float4*)(arow + k0);
    float4 f1 = *(const float4*)(arow + k0 + 4);
    float4 f2 = *(const float4*)(arow + k0 + 8);
    float4 f3 = *(const float4*)(arow + k0 + 12);
    u16x8 v0, v1;
    v0[0]=f2bf(f0.x); v0[1]=f2bf(f0.y); v0[2]=f2bf(f0.z); v0[3]=f2bf(f0.w);
    v0[4]=f2bf(f1.x); v0[5]=f2bf(f1.y); v0[6]=f2bf(f1.z); v0[7]=f2bf(f1.w);
    v1[0]=f2bf(f2.x); v1[1]=f2bf(f2.y); v1[2]=f2bf(f2.z); v1[3]=f2bf(f2.w);
    v1[4]=f2bf(f3.x); v1[5]=f2bf(f3.y); v1[6]=f2bf(f3.z); v1[7]=f2bf(f3.w);
    *(u16x8*)&As[a_m][a_kq * 16]     = v0;
    *(u16x8*)&As[a_m][a_kq * 16 + 8] = v1;
    // ---- stage B (bf16 direct) ----
    #pragma unroll
    for (int it = 0; it < 2; ++it) {
      int n = b_n + it * 32;
      int gcol = col0 + n;
      u16x8 bv;
      if (gcol < NLOG) {
        bv = *(const u16x8*)&W1T[(size_t)gcol * D_ + k0 + b_ko * 8];
      } else {
        #pragma unroll
        for (int i = 0; i < 8; ++i) bv[i] = 0;
      }
      *(u16x8*)&Bt[n][b_ko * 8] = bv;
    }
    __syncthreads();

    // ---- MFMA phase: 2 k-steps x 2x2 tiles ----
    #pragma unroll
    for (int ks = 0; ks < 2; ++ks) {
      bf16x8 a0 = *(const bf16x8*)&As[m0 + lm]     [ks * 32 + q * 8];
      bf16x8 a1 = *(const bf16x8*)&As[m0 + 16 + lm][ks * 32 + q * 8];
      bf16x8 b0 = *(const bf16x8*)&Bt[n0 + lm]     [ks * 32 + q * 8];
      bf16x8 b1 = *(const bf16x8*)&Bt[n0 + 16 + lm][ks * 32 + q * 8];
      acc[0][0] = __builtin_amdgcn_mfma_f32_16x16x32_bf16(a0, b0, acc[0][0], 0, 0, 0);
      acc[0][1] = __builtin_amdgcn_mfma_f32_16x16x32_bf16(a0, b1, acc[0][1], 0, 0, 0);
      acc[1][0] = __builtin_amdgcn_mfma_f32_16x16x32_bf16(a1, b0, acc[1][0], 0, 0, 0);
      acc[1][1] = __builtin_amdgcn_mfma_f32_16x16x32_bf16(a1, b1, acc[1][1], 0, 0, 0);
    }
    __syncthreads();
  }

  // epilogue: C/D layout col=lane&15, row=q*4+reg
  #pragma unroll
  for (int ti = 0; ti < 2; ++ti) {
    #pragma unroll
    for (int tj = 0; tj < 2; ++tj) {
      int col = col0 + n0 + tj * 16 + lm;
      if (col >= NLOG) continue;
      int pc = (col < H1_) ? col : col + 2;
      #pragma unroll
      for (int r = 0; r < 4; ++r) {
        int row = row0 + m0 + ti * 16 + q * 4 + r;
        Y[(size_t)row * YSTRIDE + pc] = acc[ti][tj][r];
      }
    }
  }
}

// ---------------------------------------------------------------------------
// pair index -> (i, j). Row-major over band mask (i<=98: 30 each; then 29..1)
// ---------------------------------------------------------------------------
__device__ inline void pair_ij(int n, int& i, int& j) {
  if (n < 2970) {
    i = n / 30;
    j = i + (n - i * 30);
  } else {
    int m = n - 2970;
    int r = 0, w = 29;
    while (m >= w) { m -= w; --w; ++r; }
    i = 99 + r;
    j = i + m;
  }
}

// ---------------------------------------------------------------------------
// Kernel 2: tall-skinny GEMM  C[pairs x 40] = relu(H)[pairs x 770] @ W2
// (unchanged from round 2)
// ---------------------------------------------------------------------------
#define PPB 128
#define CK 64
#define HS_S 68

__global__ __launch_bounds__(256) void pair_kernel(
    const float* __restrict__ Y, const int* __restrict__ spans,
    const float* __restrict__ W1, const float* __restrict__ b1,
    const float* __restrict__ W2, const float* __restrict__ b2,
    float* __restrict__ out)
{
  __shared__ float hs[PPB][HS_S];
  __shared__ float w2t[OUT_][HS_S];
  __shared__ int   pi[PPB], pj[PPB];
  __shared__ float pind[PPB];

  const int tid = threadIdx.x;
  const int bb = blockIdx.y;
  const int pair0 = blockIdx.x * PPB;
  const int tr = tid >> 3;
  const int tc = tid & 7;
  const int p0 = tr * 4;

  const float* w1c = W1 + 1536 * H1_;

  if (tid < PPB) {
    int pair = pair0 + tid;
    int i = 0, j = 0;
    if (pair < NPAIRS) pair_ij(pair, i, j);
    pi[tid] = i; pj[tid] = j;
    int s = spans[2 * bb], e = spans[2 * bb + 1];
    pind[tid] = (i == s && j == e) ? 2.0f : ((i >= s && j <= e) ? 1.0f : 0.0f);
  }
  __syncthreads();

  const int myp = tid >> 1;
  const int half = tid & 1;
  const float ind_my = pind[myp];
  const float* urow = Y + (bb * L_ + pi[myp]) * YSTRIDE;
  const float* vrow = Y + (bb * L_ + pj[myp]) * YSTRIDE + VOFF;

  float acc[4][5] = {};

  for (int k0 = 0; k0 < 768; k0 += CK) {
    __syncthreads();

    #pragma unroll
    for (int it = 0; it < (CK * OUT_) / 256; ++it) {
      int idx = tid + it * 256;
      int kk = idx / OUT_;
      int o  = idx - kk * OUT_;
      w2t[o][kk] = W2[k0 * OUT_ + idx];
    }
    {
      const float4* u4 = (const float4*)(urow + k0);
      const float4* v4 = (const float4*)(vrow + k0);
      const float4* b4 = (const float4*)(b1 + k0);
      const float4* c4 = (const float4*)(w1c + k0);
      #pragma unroll
      for (int m = 0; m < 8; ++m) {
        int qd = half * 8 + m;
        float4 u = u4[qd], v = v4[qd], bv = b4[qd], cv = c4[qd];
        float4 r;
        r.x = fmaxf(u.x + v.x + ind_my * cv.x + bv.x, 0.f);
        r.y = fmaxf(u.y + v.y + ind_my * cv.y + bv.y, 0.f);
        r.z = fmaxf(u.z + v.z + ind_my * cv.z + bv.z, 0.f);
        r.w = fmaxf(u.w + v.w + ind_my * cv.w + bv.w, 0.f);
        *(float4*)&hs[myp][qd * 4] = r;
      }
    }
    __syncthreads();

    #pragma unroll 4
    for (int kk = 0; kk < CK; kk += 4) {
      float4 h[4], wv[5];
      #pragma unroll
      for (int i = 0; i < 4; ++i) h[i] = *(const float4*)&hs[p0 + i][kk];
      #pragma unroll
      for (int j = 0; j < 5; ++j) wv[j] = *(const float4*)&w2t[tc * 5 + j][kk];
      #pragma unroll
      for (int i = 0; i < 4; ++i)
        #pragma unroll
        for (int j = 0; j < 5; ++j) {
          acc[i][j] += h[i].x * wv[j].x;
          acc[i][j] += h[i].y * wv[j].y;
          acc[i][j] += h[i].z * wv[j].z;
          acc[i][j] += h[i].w * wv[j].w;
        }
    }
  }

  {
    float wc8 = w1c[768], wc9 = w1c[769];
    float bb8 = b1[768],  bb9 = b1[769];
    float w8[5], w9[5];
    #pragma unroll
    for (int j = 0; j < 5; ++j) {
      w8[j] = W2[768 * OUT_ + tc * 5 + j];
      w9[j] = W2[769 * OUT_ + tc * 5 + j];
    }
    #pragma unroll
    for (int i = 0; i < 4; ++i) {
      int p = p0 + i;
      const float* ur = Y + (bb * L_ + pi[p]) * YSTRIDE;
      const float* vr = Y + (bb * L_ + pj[p]) * YSTRIDE + VOFF;
      float ind = pind[p];
      float h8 = fmaxf(ur[768] + vr[768] + ind * wc8 + bb8, 0.f);
      float h9 = fmaxf(ur[769] + vr[769] + ind * wc9 + bb9, 0.f);
      #pragma unroll
      for (int j = 0; j < 5; ++j)
        acc[i][j] += h8 * w8[j] + h9 * w9[j];
    }
  }

  float b2v[5];
  #pragma unroll
  for (int j = 0; j < 5; ++j) b2v[j] = b2[tc * 5 + j];

  #pragma unroll
  for (int i = 0; i < 4; ++i) {
    float l[5];
    #pragma unroll
    for (int j = 0; j < 5; ++j) l[j] = acc[i][j] + b2v[j];
    float mx = l[0];
    #pragma unroll
    for (int j = 1; j < 5; ++j) mx = fmaxf(mx, l[j]);
    mx = fmaxf(mx, __shfl_xor(mx, 1, 64));
    mx = fmaxf(mx, __shfl_xor(mx, 2, 64));
    mx = fmaxf(mx, __shfl_xor(mx, 4, 64));
    float s = 0.f;
    #pragma unroll
    for (int j = 0; j < 5; ++j) s += expf(l[j] - mx);
    s += __shfl_xor(s, 1, 64);
    s += __shfl_xor(s, 2, 64);
    s += __shfl_xor(s, 4, 64);
    float lsd = mx + logf(s);

    int pair = pair0 + p0 + i;
    if (pair < NPAIRS) {
      float* op = out + ((size_t)(bb * NPAIRS + pair)) * OUT_ + tc * 5;
      #pragma unroll
      for (int j = 0; j < 5; ++j) op[j] = l[j] - lsd;
    }
  }
}

// ---------------------------------------------------------------------------
extern "C" void kernel_launch(void* const* d_in, const int* in_sizes, int n_in,
                              void* d_out, int out_size, void* d_ws, size_t ws_size,
                              hipStream_t stream) {
  const float* hidden = (const float*)d_in[0];   // (16,129,768) f32
  const int*   spans  = (const int*)d_in[1];     // (16,2) i32
  const float* W1 = (const float*)d_in[4];       // (1537,770) f32
  const float* b1 = (const float*)d_in[5];       // (770,)
  const float* W2 = (const float*)d_in[6];       // (770,40)
  const float* b2 = (const float*)d_in[7];       // (40,)
  float* out = (float*)d_out;                    // (16,3405,40) f32

  float* Y = (float*)d_ws;                                   // 12.65 MB
  unsigned short* W1T = (unsigned short*)((char*)d_ws + (size_t)2048 * YSTRIDE * 4);  // 2.4 MB

  w1t_kernel<<<dim3(49, 24), 256, 0, stream>>>(W1, W1T);
  gemm1_mfma<<<dim3(25, 32), 256, 0, stream>>>(hidden, W1T, Y);
  pair_kernel<<<dim3((NPAIRS + PPB - 1) / PPB, B_), 256, 0, stream>>>(
      Y, spans, W1, b1, W2, b2, out);
}

// Round 4
// 154.776 us; speedup vs baseline: 3.8710x; 1.3620x over previous
//
#include <hip/hip_runtime.h>
#include <math.h>

#define B_ 16
#define L_ 128
#define D_ 768
#define H1_ 770
#define OUT_ 40
#define NPAIRS 3405     // sum over i of min(30, 128-i)
#define NLOG 1540       // logical cols of Y: U(770) || V(770)
#define YSTRIDE 1544    // padded row: U at [0,770), pad, V at [772,1542)
#define VOFF 772
#define KPAD 800        // 25 x 32 MFMA k-steps (k >= 770 zero-padded in W2T/Cv)
#define NPAD 48         // 40 outs padded to 3 x 16
#define W2T_S 800

typedef __attribute__((ext_vector_type(8))) short bf16x8;
typedef __attribute__((ext_vector_type(8))) unsigned short u16x8;
typedef __attribute__((ext_vector_type(4))) float f32x4;

__device__ inline unsigned short f2bf(float f) {
  unsigned int u = __builtin_bit_cast(unsigned int, f);
  u += 0x7fffu + ((u >> 16) & 1u);          // round-to-nearest-even
  return (unsigned short)(u >> 16);
}

// ---------------------------------------------------------------------------
// Kernel 0: W1T[n][k] = bf16( W1'[k][n] )  (unchanged from round 3)
// ---------------------------------------------------------------------------
__global__ __launch_bounds__(256) void w1t_kernel(
    const float* __restrict__ W1, unsigned short* __restrict__ W1T)
{
  __shared__ float t[32][33];
  const int tx = threadIdx.x & 31, ty = threadIdx.x >> 5;
  const int n0 = blockIdx.x * 32, k0 = blockIdx.y * 32;
  #pragma unroll
  for (int r = 0; r < 4; ++r) {
    int k = k0 + ty + r * 8, n = n0 + tx;
    float v = 0.f;
    if (n < H1_)       v = W1[k * H1_ + n];
    else if (n < NLOG) v = W1[(D_ + k) * H1_ + (n - H1_)];
    t[ty + r * 8][tx] = v;
  }
  __syncthreads();
  #pragma unroll
  for (int r = 0; r < 4; ++r) {
    int n = n0 + ty + r * 8, k = k0 + tx;
    if (n < NLOG) W1T[(size_t)n * D_ + k] = f2bf(t[tx][ty + r * 8]);
  }
}

// ---------------------------------------------------------------------------
// Kernel 0b: W2T[48][800] bf16 (transposed, zero-padded)  and
//            Cv[3][800] f32:  Cv[t][k] = b1[k] + t*w1c[k]  (0 for k>=770)
// ---------------------------------------------------------------------------
__global__ __launch_bounds__(256) void prep_kernel(
    const float* __restrict__ W1, const float* __restrict__ b1,
    const float* __restrict__ W2,
    unsigned short* __restrict__ W2T, float* __restrict__ Cv)
{
  int idx = blockIdx.x * 256 + threadIdx.x;
  const float* w1c = W1 + 1536 * H1_;
  if (idx < NPAD * KPAD) {
    int n = idx / KPAD, k = idx - n * KPAD;
    float v = (n < OUT_ && k < H1_) ? W2[k * OUT_ + n] : 0.f;
    W2T[idx] = f2bf(v);
  } else if (idx < NPAD * KPAD + 3 * KPAD) {
    int c = idx - NPAD * KPAD;
    int t = c / KPAD, k = c - t * KPAD;
    Cv[c] = (k < H1_) ? (b1[k] + (float)t * w1c[k]) : 0.f;
  }
}

// ---------------------------------------------------------------------------
// Kernel 1 (MFMA): Y[2048][pad] f32 = X @ [W1i|W1j]  (unchanged from round 3)
// ---------------------------------------------------------------------------
#define AS_S 72

__global__ __launch_bounds__(256) void gemm1_mfma(
    const float* __restrict__ hidden, const unsigned short* __restrict__ W1T,
    float* __restrict__ Y)
{
  __shared__ unsigned short As[64][AS_S];
  __shared__ unsigned short Bt[64][AS_S];
  const int tid = threadIdx.x;
  const int row0 = blockIdx.y * 64, col0 = blockIdx.x * 64;
  const int lane = tid & 63, w = tid >> 6;
  const int lm = lane & 15, q = lane >> 4;
  const int m0 = (w >> 1) * 32, n0 = (w & 1) * 32;

  f32x4 acc[2][2] = {};

  const int a_kq = tid & 3, a_m = tid >> 2;
  const int grow = row0 + a_m;
  const float* arow = hidden + (size_t)(grow + (grow >> 7) + 1) * D_ + a_kq * 16;
  const int b_ko = tid & 7, b_n = tid >> 3;

  for (int k0 = 0; k0 < D_; k0 += 64) {
    float4 f0 = *(const float4*)(arow + k0);
    float4 f1 = *(const float4*)(arow + k0 + 4);
    float4 f2 = *(const float4*)(arow + k0 + 8);
    float4 f3 = *(const float4*)(arow + k0 + 12);
    u16x8 v0, v1;
    v0[0]=f2bf(f0.x); v0[1]=f2bf(f0.y); v0[2]=f2bf(f0.z); v0[3]=f2bf(f0.w);
    v0[4]=f2bf(f1.x); v0[5]=f2bf(f1.y); v0[6]=f2bf(f1.z); v0[7]=f2bf(f1.w);
    v1[0]=f2bf(f2.x); v1[1]=f2bf(f2.y); v1[2]=f2bf(f2.z); v1[3]=f2bf(f2.w);
    v1[4]=f2bf(f3.x); v1[5]=f2bf(f3.y); v1[6]=f2bf(f3.z); v1[7]=f2bf(f3.w);
    *(u16x8*)&As[a_m][a_kq * 16]     = v0;
    *(u16x8*)&As[a_m][a_kq * 16 + 8] = v1;
    #pragma unroll
    for (int it = 0; it < 2; ++it) {
      int n = b_n + it * 32;
      int gcol = col0 + n;
      u16x8 bv;
      if (gcol < NLOG) {
        bv = *(const u16x8*)&W1T[(size_t)gcol * D_ + k0 + b_ko * 8];
      } else {
        #pragma unroll
        for (int i = 0; i < 8; ++i) bv[i] = 0;
      }
      *(u16x8*)&Bt[n][b_ko * 8] = bv;
    }
    __syncthreads();

    #pragma unroll
    for (int ks = 0; ks < 2; ++ks) {
      bf16x8 a0 = *(const bf16x8*)&As[m0 + lm]     [ks * 32 + q * 8];
      bf16x8 a1 = *(const bf16x8*)&As[m0 + 16 + lm][ks * 32 + q * 8];
      bf16x8 b0 = *(const bf16x8*)&Bt[n0 + lm]     [ks * 32 + q * 8];
      bf16x8 b1 = *(const bf16x8*)&Bt[n0 + 16 + lm][ks * 32 + q * 8];
      acc[0][0] = __builtin_amdgcn_mfma_f32_16x16x32_bf16(a0, b0, acc[0][0], 0, 0, 0);
      acc[0][1] = __builtin_amdgcn_mfma_f32_16x16x32_bf16(a0, b1, acc[0][1], 0, 0, 0);
      acc[1][0] = __builtin_amdgcn_mfma_f32_16x16x32_bf16(a1, b0, acc[1][0], 0, 0, 0);
      acc[1][1] = __builtin_amdgcn_mfma_f32_16x16x32_bf16(a1, b1, acc[1][1], 0, 0, 0);
    }
    __syncthreads();
  }

  #pragma unroll
  for (int ti = 0; ti < 2; ++ti) {
    #pragma unroll
    for (int tj = 0; tj < 2; ++tj) {
      int col = col0 + n0 + tj * 16 + lm;
      if (col >= NLOG) continue;
      int pc = (col < H1_) ? col : col + 2;
      #pragma unroll
      for (int r = 0; r < 4; ++r) {
        int row = row0 + m0 + ti * 16 + q * 4 + r;
        Y[(size_t)row * YSTRIDE + pc] = acc[ti][tj][r];
      }
    }
  }
}

// ---------------------------------------------------------------------------
// pair index -> (i, j)
// ---------------------------------------------------------------------------
__device__ inline void pair_ij(int n, int& i, int& j) {
  if (n < 2970) {
    i = n / 30;
    j = i + (n - i * 30);
  } else {
    int m = n - 2970;
    int r = 0, w = 29;
    while (m >= w) { m -= w; --w; ++r; }
    i = 99 + r;
    j = i + m;
  }
}

// ---------------------------------------------------------------------------
// Kernel 2 (MFMA, LDS-free): per wave, 16 pairs x 48 outs.
// A-frag (h rows) assembled in registers from float4 loads of U/V/Cv;
// B-frags read straight from W2T (L1/L2-hot). 25 k-steps of 32.
// k>=770 contributes 0 via W2T/Cv zero-padding (garbage h is finite).
// ---------------------------------------------------------------------------
__global__ __launch_bounds__(256) void pair_mfma(
    const float* __restrict__ Y, const int* __restrict__ spans,
    const unsigned short* __restrict__ W2T, const float* __restrict__ Cv,
    const float* __restrict__ b2, float* __restrict__ out)
{
  const int tid = threadIdx.x;
  const int bb = blockIdx.y;
  const int pair0 = blockIdx.x * 64;
  const int lane = tid & 63, w = tid >> 6;
  const int lm = lane & 15, q = lane >> 4;

  // this lane's A-side pair
  int apair = pair0 + w * 16 + lm;
  int ai = 0, aj = 0;
  if (apair < NPAIRS) pair_ij(apair, ai, aj);
  const int s = spans[2 * bb], e = spans[2 * bb + 1];
  const int ind = (ai == s && aj == e) ? 2 : ((ai >= s && aj <= e) ? 1 : 0);

  const float* uptr = Y + (size_t)(bb * L_ + ai) * YSTRIDE + q * 8;
  const float* vptr = Y + (size_t)(bb * L_ + aj) * YSTRIDE + VOFF + q * 8;
  const float* cptr = Cv + ind * KPAD + q * 8;
  const unsigned short* bp0 = W2T + (0 * 16 + lm) * W2T_S + q * 8;
  const unsigned short* bp1 = W2T + (1 * 16 + lm) * W2T_S + q * 8;
  const unsigned short* bp2 = W2T + (2 * 16 + lm) * W2T_S + q * 8;

  f32x4 acc0 = {}, acc1 = {}, acc2 = {};

  #pragma unroll 5
  for (int ks = 0; ks < 25; ++ks) {
    const int ko = ks * 32;
    float4 u0 = *(const float4*)(uptr + ko);
    float4 u1 = *(const float4*)(uptr + ko + 4);
    float4 v0 = *(const float4*)(vptr + ko);
    float4 v1 = *(const float4*)(vptr + ko + 4);
    float4 c0 = *(const float4*)(cptr + ko);
    float4 c1 = *(const float4*)(cptr + ko + 4);
    u16x8 hh;
    hh[0] = f2bf(fmaxf(u0.x + v0.x + c0.x, 0.f));
    hh[1] = f2bf(fmaxf(u0.y + v0.y + c0.y, 0.f));
    hh[2] = f2bf(fmaxf(u0.z + v0.z + c0.z, 0.f));
    hh[3] = f2bf(fmaxf(u0.w + v0.w + c0.w, 0.f));
    hh[4] = f2bf(fmaxf(u1.x + v1.x + c1.x, 0.f));
    hh[5] = f2bf(fmaxf(u1.y + v1.y + c1.y, 0.f));
    hh[6] = f2bf(fmaxf(u1.z + v1.z + c1.z, 0.f));
    hh[7] = f2bf(fmaxf(u1.w + v1.w + c1.w, 0.f));
    bf16x8 a = __builtin_bit_cast(bf16x8, hh);
    bf16x8 bf0 = *(const bf16x8*)(bp0 + ko);
    bf16x8 bf1 = *(const bf16x8*)(bp1 + ko);
    bf16x8 bf2 = *(const bf16x8*)(bp2 + ko);
    acc0 = __builtin_amdgcn_mfma_f32_16x16x32_bf16(a, bf0, acc0, 0, 0, 0);
    acc1 = __builtin_amdgcn_mfma_f32_16x16x32_bf16(a, bf1, acc1, 0, 0, 0);
    acc2 = __builtin_amdgcn_mfma_f32_16x16x32_bf16(a, bf2, acc2, 0, 0, 0);
  }

  // epilogue: C/D layout col=lane&15, row=q*4+r. +b2, log-softmax over the
  // 16-lane group (shfl_xor 1/2/4/8 stays within lanes q*16..q*16+15).
  const float b2v0 = b2[lm];
  const float b2v1 = b2[16 + lm];
  const float b2v2 = (lm < 8) ? b2[32 + lm] : 0.f;

  #pragma unroll
  for (int r = 0; r < 4; ++r) {
    float l0 = acc0[r] + b2v0;
    float l1 = acc1[r] + b2v1;
    float l2 = (lm < 8) ? (acc2[r] + b2v2) : -INFINITY;
    float mx = fmaxf(fmaxf(l0, l1), l2);
    mx = fmaxf(mx, __shfl_xor(mx, 1));
    mx = fmaxf(mx, __shfl_xor(mx, 2));
    mx = fmaxf(mx, __shfl_xor(mx, 4));
    mx = fmaxf(mx, __shfl_xor(mx, 8));
    float sm = expf(l0 - mx) + expf(l1 - mx) + ((lm < 8) ? expf(l2 - mx) : 0.f);
    sm += __shfl_xor(sm, 1);
    sm += __shfl_xor(sm, 2);
    sm += __shfl_xor(sm, 4);
    sm += __shfl_xor(sm, 8);
    float lsd = mx + logf(sm);

    int pair = pair0 + w * 16 + q * 4 + r;
    if (pair < NPAIRS) {
      float* op = out + ((size_t)bb * NPAIRS + pair) * OUT_;
      op[lm]      = l0 - lsd;
      op[16 + lm] = l1 - lsd;
      if (lm < 8) op[32 + lm] = l2 - lsd;
    }
  }
}

// ---------------------------------------------------------------------------
extern "C" void kernel_launch(void* const* d_in, const int* in_sizes, int n_in,
                              void* d_out, int out_size, void* d_ws, size_t ws_size,
                              hipStream_t stream) {
  const float* hidden = (const float*)d_in[0];   // (16,129,768) f32
  const int*   spans  = (const int*)d_in[1];     // (16,2) i32
  const float* W1 = (const float*)d_in[4];       // (1537,770) f32
  const float* b1 = (const float*)d_in[5];       // (770,)
  const float* W2 = (const float*)d_in[6];       // (770,40)
  const float* b2 = (const float*)d_in[7];       // (40,)
  float* out = (float*)d_out;                    // (16,3405,40) f32

  // ws layout (Y has one spare row: pair_mfma's V-tail k-reads on the last
  // row overrun by <32 floats — keep them inside poisoned-but-finite space)
  float* Y = (float*)d_ws;
  size_t yBytes   = (size_t)2049 * YSTRIDE * 4;                 // 12.65 MB
  unsigned short* W1T = (unsigned short*)((char*)d_ws + yBytes);    // 2.37 MB
  size_t w1tBytes = (size_t)NLOG * D_ * 2;
  unsigned short* W2T = (unsigned short*)((char*)W1T + w1tBytes);   // 76.8 KB
  float* Cv = (float*)((char*)W2T + (size_t)NPAD * KPAD * 2);       // 9.6 KB

  w1t_kernel<<<dim3(49, 24), 256, 0, stream>>>(W1, W1T);
  prep_kernel<<<dim3((NPAD * KPAD + 3 * KPAD + 255) / 256), 256, 0, stream>>>(
      W1, b1, W2, W2T, Cv);
  gemm1_mfma<<<dim3(25, 32), 256, 0, stream>>>(hidden, W1T, Y);
  pair_mfma<<<dim3((NPAIRS + 63) / 64, B_), 256, 0, stream>>>(
      Y, spans, W2T, Cv, b2, out);
}

// Round 5
// 134.089 us; speedup vs baseline: 4.4682x; 1.1543x over previous
//
#include <hip/hip_runtime.h>
#include <math.h>

#define B_ 16
#define L_ 128
#define D_ 768
#define H1_ 770
#define OUT_ 40
#define NPAIRS 3405     // sum over i of min(30, 128-i)
#define NLOG 1540       // logical cols of Y: U(770) || V(770)
#define YSB 1552        // bf16 Y row stride in shorts (16B-aligned rows)
#define VOFFB 776       // V part at +776 shorts (1552 B, 16B-aligned)
#define KPAD 800        // 25 x 32 MFMA k-steps (k >= 770 zero-padded in W2T/Cv)
#define NPAD 48         // 40 outs padded to 3 x 16
#define W2T_S 800
#define W1TROWS 1600    // W1T rows padded (zeros in [1540,1600)) for safe staging

typedef __attribute__((ext_vector_type(8))) short bf16x8;
typedef __attribute__((ext_vector_type(8))) unsigned short u16x8;
typedef __attribute__((ext_vector_type(4))) float f32x4;
typedef __attribute__((ext_vector_type(4))) unsigned int u32x4;

__device__ inline unsigned short f2bf(float f) {
  unsigned int u = __builtin_bit_cast(unsigned int, f);
  u += 0x7fffu + ((u >> 16) & 1u);          // round-to-nearest-even
  return (unsigned short)(u >> 16);
}
__device__ inline float bf2f(unsigned short x) {
  return __builtin_bit_cast(float, (unsigned int)x << 16);
}

#if __has_builtin(__builtin_amdgcn_cvt_pk_bf16_f32)
typedef __attribute__((ext_vector_type(2))) __bf16 bf16x2_t;
__device__ inline unsigned int pack_bf16(float lo, float hi) {
  bf16x2_t r = __builtin_amdgcn_cvt_pk_bf16_f32(lo, hi);
  return __builtin_bit_cast(unsigned int, r);
}
#else
__device__ inline unsigned int pack_bf16(float lo, float hi) {
  return (unsigned int)f2bf(lo) | ((unsigned int)f2bf(hi) << 16);
}
#endif

// async global->LDS, 16B per lane; LDS dest = wave-uniform base + lane*16
typedef const __attribute__((address_space(1))) void* gas_t;
typedef __attribute__((address_space(3))) void* las_t;
__device__ inline void gl2lds16(const void* g, void* l) {
  __builtin_amdgcn_global_load_lds((gas_t)g, (las_t)l, 16, 0, 0);
}

// ---------------------------------------------------------------------------
// Kernel 0a: merged elementwise prep.
//   blocks [0, XCVT part): Xb[2048][768] = bf16(hidden rows, skipping CLS)
//   tail: W2T[48][800] bf16 (transposed, zero-padded) and
//         Cv[3][800] f32: Cv[t][k] = b1[k] + t*w1c[k] (0 for k>=770)
// ---------------------------------------------------------------------------
#define XCVT_N (2048 * 192)

__global__ __launch_bounds__(256) void prep_all(
    const float* __restrict__ hidden, const float* __restrict__ W1,
    const float* __restrict__ b1, const float* __restrict__ W2,
    unsigned short* __restrict__ Xb, unsigned short* __restrict__ W2T,
    float* __restrict__ Cv)
{
  int idx = blockIdx.x * 256 + threadIdx.x;
  if (idx < XCVT_N) {
    int m = idx / 192;
    int c = idx - m * 192;
    float4 f = *(const float4*)(hidden + (size_t)(m + (m >> 7) + 1) * D_ + c * 4);
    ushort4 o;
    o.x = f2bf(f.x); o.y = f2bf(f.y); o.z = f2bf(f.z); o.w = f2bf(f.w);
    *(ushort4*)(Xb + (size_t)m * D_ + c * 4) = o;
    return;
  }
  idx -= XCVT_N;
  const float* w1c = W1 + 1536 * H1_;
  if (idx < NPAD * KPAD) {
    int n = idx / KPAD, k = idx - n * KPAD;
    float v = (n < OUT_ && k < H1_) ? W2[k * OUT_ + n] : 0.f;
    W2T[idx] = f2bf(v);
  } else if (idx < NPAD * KPAD + 3 * KPAD) {
    int c = idx - NPAD * KPAD;
    int t = c / KPAD, k = c - t * KPAD;
    Cv[c] = (k < H1_) ? (b1[k] + (float)t * w1c[k]) : 0.f;
  }
}

// ---------------------------------------------------------------------------
// Kernel 0b: W1T[n][k] = bf16( W1'[k][n] ), rows [1540,1600) zero-filled.
// ---------------------------------------------------------------------------
__global__ __launch_bounds__(256) void w1t_kernel(
    const float* __restrict__ W1, unsigned short* __restrict__ W1T)
{
  __shared__ float t[32][33];
  const int tx = threadIdx.x & 31, ty = threadIdx.x >> 5;
  const int n0 = blockIdx.x * 32, k0 = blockIdx.y * 32;
  #pragma unroll
  for (int r = 0; r < 4; ++r) {
    int k = k0 + ty + r * 8, n = n0 + tx;
    float v = 0.f;
    if (n < H1_)       v = W1[k * H1_ + n];
    else if (n < NLOG) v = W1[(D_ + k) * H1_ + (n - H1_)];
    t[ty + r * 8][tx] = v;
  }
  __syncthreads();
  #pragma unroll
  for (int r = 0; r < 4; ++r) {
    int n = n0 + ty + r * 8, k = k0 + tx;
    W1T[(size_t)n * D_ + k] = f2bf(t[tx][ty + r * 8]);   // n < 1600 always
  }
}

// ---------------------------------------------------------------------------
// Kernel 1 (MFMA, async staging): Yb[2048][YSB] bf16 = Xb @ W1T^T
// 64x64 tile, BK=64, 4 waves x (2x2 16x16x32 frags), global_load_lds width=16.
// ---------------------------------------------------------------------------
__global__ __launch_bounds__(256) void gemm1_mfma(
    const unsigned short* __restrict__ Xb, const unsigned short* __restrict__ W1T,
    unsigned short* __restrict__ Yb)
{
  __shared__ unsigned short As[64][64];   // 8 KB
  __shared__ unsigned short Bs[64][64];   // 8 KB
  const int tid = threadIdx.x;
  const int lane = tid & 63, w = tid >> 6;
  const int lm = lane & 15, q = lane >> 4;
  const int row0 = blockIdx.y * 64, col0 = blockIdx.x * 64;
  const int m0 = (w >> 1) * 32, n0 = (w & 1) * 32;

  // staging: wave w owns tile rows [w*16, w*16+16); lane l -> row +l/8, 16B chunk l%8
  const int srow = w * 16 + (lane >> 3);
  const int schunk = (lane & 7) * 8;
  const unsigned short* ga = Xb  + (size_t)(row0 + srow) * D_ + schunk;
  const unsigned short* gb = W1T + (size_t)(col0 + srow) * D_ + schunk;
  unsigned short* la = &As[w * 16][0];    // wave-uniform LDS bases
  unsigned short* lb = &Bs[w * 16][0];

  f32x4 acc[2][2] = {};

  for (int k0 = 0; k0 < D_; k0 += 64) {
    gl2lds16(ga + k0,           la);
    gl2lds16(ga + k0 + 8 * D_,  la + 8 * 64);
    gl2lds16(gb + k0,           lb);
    gl2lds16(gb + k0 + 8 * D_,  lb + 8 * 64);
    __syncthreads();

    #pragma unroll
    for (int ks = 0; ks < 2; ++ks) {
      bf16x8 a0 = *(const bf16x8*)&As[m0 + lm]     [ks * 32 + q * 8];
      bf16x8 a1 = *(const bf16x8*)&As[m0 + 16 + lm][ks * 32 + q * 8];
      bf16x8 b0 = *(const bf16x8*)&Bs[n0 + lm]     [ks * 32 + q * 8];
      bf16x8 b1 = *(const bf16x8*)&Bs[n0 + 16 + lm][ks * 32 + q * 8];
      acc[0][0] = __builtin_amdgcn_mfma_f32_16x16x32_bf16(a0, b0, acc[0][0], 0, 0, 0);
      acc[0][1] = __builtin_amdgcn_mfma_f32_16x16x32_bf16(a0, b1, acc[0][1], 0, 0, 0);
      acc[1][0] = __builtin_amdgcn_mfma_f32_16x16x32_bf16(a1, b0, acc[1][0], 0, 0, 0);
      acc[1][1] = __builtin_amdgcn_mfma_f32_16x16x32_bf16(a1, b1, acc[1][1], 0, 0, 0);
    }
    __syncthreads();
  }

  // epilogue: C/D layout col=lane&15, row=q*4+r; store bf16
  #pragma unroll
  for (int ti = 0; ti < 2; ++ti) {
    #pragma unroll
    for (int tj = 0; tj < 2; ++tj) {
      int col = col0 + n0 + tj * 16 + lm;
      if (col >= NLOG) continue;
      int pc = (col < H1_) ? col : col + (VOFFB - H1_);
      #pragma unroll
      for (int r = 0; r < 4; ++r) {
        int row = row0 + m0 + ti * 16 + q * 4 + r;
        Yb[(size_t)row * YSB + pc] = f2bf(acc[ti][tj][r]);
      }
    }
  }
}

// ---------------------------------------------------------------------------
// pair index -> (i, j)
// ---------------------------------------------------------------------------
__device__ inline void pair_ij(int n, int& i, int& j) {
  if (n < 2970) {
    i = n / 30;
    j = i + (n - i * 30);
  } else {
    int m = n - 2970;
    int r = 0, w = 29;
    while (m >= w) { m -= w; --w; ++r; }
    i = 99 + r;
    j = i + m;
  }
}

// ---------------------------------------------------------------------------
// Kernel 2 (MFMA, LDS-free): per wave, 16 pairs x 48 outs. bf16 Y inputs:
// one 16B U-load + one 16B V-load per k-step. k>=770 contributes 0 via
// W2T/Cv zero-padding (garbage h is finite: 0xAA poison is a finite bf16).
// ---------------------------------------------------------------------------
__global__ __launch_bounds__(256) void pair_mfma(
    const unsigned short* __restrict__ Yb, const int* __restrict__ spans,
    const unsigned short* __restrict__ W2T, const float* __restrict__ Cv,
    const float* __restrict__ b2, float* __restrict__ out)
{
  const int tid = threadIdx.x;
  const int bb = blockIdx.y;
  const int pair0 = blockIdx.x * 64;
  const int lane = tid & 63, w = tid >> 6;
  const int lm = lane & 15, q = lane >> 4;

  int apair = pair0 + w * 16 + lm;
  int ai = 0, aj = 0;
  if (apair < NPAIRS) pair_ij(apair, ai, aj);
  const int s = spans[2 * bb], e = spans[2 * bb + 1];
  const int ind = (ai == s && aj == e) ? 2 : ((ai >= s && aj <= e) ? 1 : 0);

  const unsigned short* uptr = Yb + (size_t)(bb * L_ + ai) * YSB + q * 8;
  const unsigned short* vptr = Yb + (size_t)(bb * L_ + aj) * YSB + VOFFB + q * 8;
  const float* cptr = Cv + ind * KPAD + q * 8;
  const unsigned short* bp0 = W2T + (0 * 16 + lm) * W2T_S + q * 8;
  const unsigned short* bp1 = W2T + (1 * 16 + lm) * W2T_S + q * 8;
  const unsigned short* bp2 = W2T + (2 * 16 + lm) * W2T_S + q * 8;

  f32x4 acc0 = {}, acc1 = {}, acc2 = {};

  #pragma unroll 5
  for (int ks = 0; ks < 25; ++ks) {
    const int ko = ks * 32;
    u16x8 uu = *(const u16x8*)(uptr + ko);
    u16x8 vv = *(const u16x8*)(vptr + ko);
    float4 c0 = *(const float4*)(cptr + ko);
    float4 c1 = *(const float4*)(cptr + ko + 4);
    float h0 = fmaxf(bf2f(uu[0]) + bf2f(vv[0]) + c0.x, 0.f);
    float h1 = fmaxf(bf2f(uu[1]) + bf2f(vv[1]) + c0.y, 0.f);
    float h2 = fmaxf(bf2f(uu[2]) + bf2f(vv[2]) + c0.z, 0.f);
    float h3 = fmaxf(bf2f(uu[3]) + bf2f(vv[3]) + c0.w, 0.f);
    float h4 = fmaxf(bf2f(uu[4]) + bf2f(vv[4]) + c1.x, 0.f);
    float h5 = fmaxf(bf2f(uu[5]) + bf2f(vv[5]) + c1.y, 0.f);
    float h6 = fmaxf(bf2f(uu[6]) + bf2f(vv[6]) + c1.z, 0.f);
    float h7 = fmaxf(bf2f(uu[7]) + bf2f(vv[7]) + c1.w, 0.f);
    u32x4 hp;
    hp[0] = pack_bf16(h0, h1);
    hp[1] = pack_bf16(h2, h3);
    hp[2] = pack_bf16(h4, h5);
    hp[3] = pack_bf16(h6, h7);
    bf16x8 a = __builtin_bit_cast(bf16x8, hp);
    bf16x8 bf0 = *(const bf16x8*)(bp0 + ko);
    bf16x8 bf1 = *(const bf16x8*)(bp1 + ko);
    bf16x8 bf2v = *(const bf16x8*)(bp2 + ko);
    acc0 = __builtin_amdgcn_mfma_f32_16x16x32_bf16(a, bf0, acc0, 0, 0, 0);
    acc1 = __builtin_amdgcn_mfma_f32_16x16x32_bf16(a, bf1, acc1, 0, 0, 0);
    acc2 = __builtin_amdgcn_mfma_f32_16x16x32_bf16(a, bf2v, acc2, 0, 0, 0);
  }

  // epilogue: C/D col=lane&15, row=q*4+r; +b2, 16-lane-group log-softmax
  const float b2v0 = b2[lm];
  const float b2v1 = b2[16 + lm];
  const float b2v2 = (lm < 8) ? b2[32 + lm] : 0.f;

  #pragma unroll
  for (int r = 0; r < 4; ++r) {
    float l0 = acc0[r] + b2v0;
    float l1 = acc1[r] + b2v1;
    float l2 = (lm < 8) ? (acc2[r] + b2v2) : -INFINITY;
    float mx = fmaxf(fmaxf(l0, l1), l2);
    mx = fmaxf(mx, __shfl_xor(mx, 1));
    mx = fmaxf(mx, __shfl_xor(mx, 2));
    mx = fmaxf(mx, __shfl_xor(mx, 4));
    mx = fmaxf(mx, __shfl_xor(mx, 8));
    float sm = expf(l0 - mx) + expf(l1 - mx) + ((lm < 8) ? expf(l2 - mx) : 0.f);
    sm += __shfl_xor(sm, 1);
    sm += __shfl_xor(sm, 2);
    sm += __shfl_xor(sm, 4);
    sm += __shfl_xor(sm, 8);
    float lsd = mx + logf(sm);

    int pair = pair0 + w * 16 + q * 4 + r;
    if (pair < NPAIRS) {
      float* op = out + ((size_t)bb * NPAIRS + pair) * OUT_;
      op[lm]      = l0 - lsd;
      op[16 + lm] = l1 - lsd;
      if (lm < 8) op[32 + lm] = l2 - lsd;
    }
  }
}

// ---------------------------------------------------------------------------
extern "C" void kernel_launch(void* const* d_in, const int* in_sizes, int n_in,
                              void* d_out, int out_size, void* d_ws, size_t ws_size,
                              hipStream_t stream) {
  const float* hidden = (const float*)d_in[0];   // (16,129,768) f32
  const int*   spans  = (const int*)d_in[1];     // (16,2) i32
  const float* W1 = (const float*)d_in[4];       // (1537,770) f32
  const float* b1 = (const float*)d_in[5];       // (770,)
  const float* W2 = (const float*)d_in[6];       // (770,40)
  const float* b2 = (const float*)d_in[7];       // (40,)
  float* out = (float*)d_out;                    // (16,3405,40) f32

  // workspace layout (256B-aligned slabs). Yb gets one spare row: pair_mfma's
  // V-tail reads on the last row overrun by <48 shorts into poisoned-but-
  // finite space.
  char* base = (char*)d_ws;
  size_t off = 0;
  auto take = [&](size_t bytes) {
    char* p = base + off;
    off = (off + bytes + 255) & ~(size_t)255;
    return p;
  };
  unsigned short* Yb  = (unsigned short*)take((size_t)2049 * YSB * 2);      // 6.36 MB
  unsigned short* Xb  = (unsigned short*)take((size_t)2048 * D_ * 2);       // 3.15 MB
  unsigned short* W1T = (unsigned short*)take((size_t)W1TROWS * D_ * 2);    // 2.46 MB
  unsigned short* W2T = (unsigned short*)take((size_t)NPAD * KPAD * 2);     // 76.8 KB
  float*          Cv  = (float*)take((size_t)3 * KPAD * 4);                 // 9.6 KB

  prep_all<<<dim3((XCVT_N + NPAD * KPAD + 3 * KPAD + 255) / 256), 256, 0, stream>>>(
      hidden, W1, b1, W2, Xb, W2T, Cv);
  w1t_kernel<<<dim3(50, 24), 256, 0, stream>>>(W1, W1T);
  gemm1_mfma<<<dim3(25, 32), 256, 0, stream>>>(Xb, W1T, Yb);
  pair_mfma<<<dim3((NPAIRS + 63) / 64, B_), 256, 0, stream>>>(
      Yb, spans, W2T, Cv, b2, out);
}